// Round 4
// baseline (171.181 us; speedup 1.0000x reference)
//
#include <hip/hip_runtime.h>

// FullyConnectedTP (e3nn FCTP, MUL=16) — R4: R1 structure (best, 158.7us)
// + non-temporal weight/u loads and non-temporal output store.
// Weight stream is 800MB read-once: nt bypasses cache allocation.
//
// out[n, j] j<16      = PW0 * sum_u ( w1[n,u,j]*u0[u]*v0 + w4[n,u,j]*d4[u]*inv3 )
// out[n, 16+3w+k]     = PW1 * sum_u ( w2[n,u,w]*u0[u]*v1[k]*inv3 + w3[n,u,w]*u1[u,k]*v0*inv3 )
// d4[u] = dot(u1[u,:], v1); weight reshaped (N,4,16,16) row-major.

__global__ __launch_bounds__(256) void fctp_kernel(
    const float* __restrict__ u,
    const float* __restrict__ v,
    const float* __restrict__ wgt,
    float* __restrict__ out,
    int N)
{
    constexpr float INV_SQRT3 = 0.57735026918962576451f; // 1/sqrt(3)
    constexpr float PW0 = 0.17677669529663688110f;       // sqrt(1/32)
    constexpr float PW1 = 0.30618621784789726f;          // sqrt(3/32)

    const int lane = threadIdx.x & 63;
    const int wv   = threadIdx.x >> 6;      // wave within block (0..3)
    int n = blockIdx.x * 4 + wv;
    if (n >= N) n = N - 1;                  // benign, deterministic

    // per-wave LDS: [0..63] = u row, [64..79] = d4[u], [80..83] = v row
    __shared__ float sh[4][84];
    float* s = sh[wv];

    // ---- stage u and v (coalesced; u is read-once -> nt) ----
    s[lane] = __builtin_nontemporal_load(u + (size_t)n * 64 + lane);
    if (lane < 4) s[80 + lane] = v[(size_t)n * 4 + lane];
    __syncthreads();

    // ---- d4[u] = dot(u1[u,:], v1) by lanes 0..15 ----
    if (lane < 16) {
        const int b = 16 + 3 * lane;
        s[64 + lane] = s[b] * s[81] + s[b + 1] * s[82] + s[b + 2] * s[83];
    }
    __syncthreads();

    // ---- per-lane constants ----
    const bool is0 = (lane < 16);
    const int  o    = lane - 16;
    const int  wcol = is0 ? lane : (o / 3);
    const int  k    = is0 ? 0    : (o - 3 * wcol);
    const float v0  = s[80];
    const float p   = is0 ? v0        : s[81 + k] * INV_SQRT3;
    const float q   = is0 ? INV_SQRT3 : v0 * INV_SQRT3;
    const int offA = is0 ? wcol         : (256 + wcol); // w1 : w2
    const int offB = is0 ? (768 + wcol) : (512 + wcol); // w4 : w3
    const int offY  = is0 ? 64 : (16 + k);              // d4[u] vs u1[u][k]
    const int ystep = is0 ? 1 : 3;

    const float* wp = wgt + (size_t)n * 1024;

    float acc = 0.0f;
#pragma unroll
    for (int uu = 0; uu < 16; ++uu) {
        const float X  = s[uu];
        const float Y  = s[offY + uu * ystep];
        const float wa = __builtin_nontemporal_load(wp + offA + uu * 16);
        const float wb = __builtin_nontemporal_load(wp + offB + uu * 16);
        acc = fmaf(wa, X * p, acc);
        acc = fmaf(wb, Y * q, acc);
    }

    __builtin_nontemporal_store((is0 ? PW0 : PW1) * acc,
                                out + (size_t)n * 64 + lane);
}

extern "C" void kernel_launch(void* const* d_in, const int* in_sizes, int n_in,
                              void* d_out, int out_size, void* d_ws, size_t ws_size,
                              hipStream_t stream)
{
    const float* u   = (const float*)d_in[0];
    const float* v   = (const float*)d_in[1];
    const float* wgt = (const float*)d_in[2];
    float* out = (float*)d_out;

    const int N = in_sizes[1] / 4;      // v is (N,4)
    const int blocks = (N + 3) / 4;     // 4 edges (waves) per 256-thread block
    fctp_kernel<<<blocks, 256, 0, stream>>>(u, v, wgt, out, N);
}

// Round 5
// 163.837 us; speedup vs baseline: 1.0448x; 1.0448x over previous
//
#include <hip/hip_runtime.h>

// FullyConnectedTP (e3nn FCTP, MUL=16) — R5: R1 structure, 2 edges per wave,
// software-pipelined (all 64 weight loads issued before first FMA so edge-1
// loads remain in flight during edge-0 compute). Amortizes barriers / staging
// / epilogue 2x per edge.
//
// out[n, j] j<16   = PW0 * sum_u ( w1[n,u,j]*u0[u]*v0 + w4[n,u,j]*d4[u]*inv3 )
// out[n, 16+3w+k]  = PW1 * sum_u ( w2[n,u,w]*u0[u]*v1[k]*inv3 + w3[n,u,w]*u1[u,k]*v0*inv3 )
// d4[u] = dot(u1[u,:], v1); weight (N,4,16,16) row-major. lane == out index.

__global__ __launch_bounds__(256) void fctp_kernel(
    const float* __restrict__ u,
    const float* __restrict__ v,
    const float* __restrict__ wgt,
    float* __restrict__ out,
    int N)
{
    constexpr float INV_SQRT3 = 0.57735026918962576451f; // 1/sqrt(3)
    constexpr float PW0 = 0.17677669529663688110f;       // sqrt(1/32)
    constexpr float PW1 = 0.30618621784789726f;          // sqrt(3/32)

    const int lane = threadIdx.x & 63;
    const int wv   = threadIdx.x >> 6;       // wave within block (0..3)
    int n0 = (blockIdx.x * 4 + wv) * 2;      // first edge of this wave's pair
    if (n0 + 1 >= N) n0 = N - 2;             // benign, deterministic (N even)

    // per-wave LDS: two coefficient blocks of 84 floats
    // [0..63]=u row, [64..79]=d4, [80..83]=v row
    __shared__ float sh[4][168];
    float* s0 = sh[wv];
    float* s1 = sh[wv] + 84;

    // ---- stage u rows (2 coalesced loads) and v rows (8 contiguous floats) ----
    s0[lane] = u[(size_t)n0 * 64 + lane];
    s1[lane] = u[(size_t)n0 * 64 + 64 + lane];
    if (lane < 8) {
        // v[n0*4 .. n0*4+7] covers both edges' v rows
        float vl = v[(size_t)n0 * 4 + lane];
        if (lane < 4) s0[80 + lane] = vl; else s1[76 + lane] = vl; // 80+(lane-4)
    }
    __syncthreads();

    // ---- d4[u]: lanes 0..15 edge0, lanes 32..47 edge1 (parallel) ----
    if (lane < 16) {
        const int b = 16 + 3 * lane;
        s0[64 + lane] = s0[b] * s0[81] + s0[b + 1] * s0[82] + s0[b + 2] * s0[83];
    } else if (lane >= 32 && lane < 48) {
        const int l = lane - 32;
        const int b = 16 + 3 * l;
        s1[64 + l] = s1[b] * s1[81] + s1[b + 1] * s1[82] + s1[b + 2] * s1[83];
    }
    __syncthreads();

    // ---- per-lane constants (same offsets for both edges) ----
    const bool is0 = (lane < 16);
    const int  o    = lane - 16;
    const int  wcol = is0 ? lane : (o / 3);
    const int  k    = is0 ? 0    : (o - 3 * wcol);
    const int offA  = is0 ? wcol         : (256 + wcol); // w1 : w2
    const int offB  = is0 ? (768 + wcol) : (512 + wcol); // w4 : w3
    const int offY  = is0 ? 64 : (16 + k);               // d4[u] vs u1[u][k]
    const int ystep = is0 ? 1 : 3;

    const float p0 = is0 ? s0[80] : s0[81 + k] * INV_SQRT3;
    const float q0 = is0 ? INV_SQRT3 : s0[80] * INV_SQRT3;
    const float p1 = is0 ? s1[80] : s1[81 + k] * INV_SQRT3;
    const float q1 = is0 ? INV_SQRT3 : s1[80] * INV_SQRT3;

    const float* wp0 = wgt + (size_t)n0 * 1024;
    const float* wp1 = wp0 + 1024;

    // ---- issue ALL weight loads for both edges before any FMA ----
    float wA0[16], wB0[16], wA1[16], wB1[16];
#pragma unroll
    for (int uu = 0; uu < 16; ++uu) {
        wA0[uu] = wp0[offA + uu * 16];
        wB0[uu] = wp0[offB + uu * 16];
    }
#pragma unroll
    for (int uu = 0; uu < 16; ++uu) {
        wA1[uu] = wp1[offA + uu * 16];
        wB1[uu] = wp1[offB + uu * 16];
    }

    // ---- edge 0 compute + store (edge-1 loads still in flight) ----
    float acc0 = 0.0f;
#pragma unroll
    for (int uu = 0; uu < 16; ++uu) {
        acc0 = fmaf(wA0[uu], s0[uu] * p0, acc0);
        acc0 = fmaf(wB0[uu], s0[offY + uu * ystep] * q0, acc0);
    }
    const float scale = is0 ? PW0 : PW1;
    out[(size_t)n0 * 64 + lane] = scale * acc0;

    // ---- edge 1 compute + store ----
    float acc1 = 0.0f;
#pragma unroll
    for (int uu = 0; uu < 16; ++uu) {
        acc1 = fmaf(wA1[uu], s1[uu] * p1, acc1);
        acc1 = fmaf(wB1[uu], s1[offY + uu * ystep] * q1, acc1);
    }
    out[(size_t)n0 * 64 + 64 + lane] = scale * acc1;
}

extern "C" void kernel_launch(void* const* d_in, const int* in_sizes, int n_in,
                              void* d_out, int out_size, void* d_ws, size_t ws_size,
                              hipStream_t stream)
{
    const float* u   = (const float*)d_in[0];
    const float* v   = (const float*)d_in[1];
    const float* wgt = (const float*)d_in[2];
    float* out = (float*)d_out;

    const int N = in_sizes[1] / 4;        // v is (N,4)
    const int blocks = (N + 7) / 8;       // 4 waves/block, 2 edges/wave
    fctp_kernel<<<blocks, 256, 0, stream>>>(u, v, wgt, out, N);
}

// Round 6
// 158.722 us; speedup vs baseline: 1.0785x; 1.0322x over previous
//
#include <hip/hip_runtime.h>

// FullyConnectedTP (e3nn FCTP, MUL=16) — FINAL: revert to R1 structure,
// the best of 5 structural variants (158.7us; LDS-tile 163.2, reg-float4+DPP
// 164.9, nontemporal 171.2, 2-edge pipeline 163.8).
// 924.8 MB compulsory HBM traffic @ 5.83 TB/s = 93% of measured copy ceiling
// -> memory-roofline-bound.
//
// out[n, j] j<16   = PW0 * sum_u ( w1[n,u,j]*u0[u]*v0 + w4[n,u,j]*d4[u]*inv3 )
// out[n, 16+3w+k]  = PW1 * sum_u ( w2[n,u,w]*u0[u]*v1[k]*inv3 + w3[n,u,w]*u1[u,k]*v0*inv3 )
// d4[u] = dot(u1[u,:], v1); weight reshaped (N,4,16,16) row-major.
//
// One wave per edge, lane = output element. Weight columns read via wave-wide
// dword loads (each instruction covers full 64B rows across the wave) -> every
// weight byte fetched exactly once. Per-edge coefficients staged in LDS.

__global__ __launch_bounds__(256) void fctp_kernel(
    const float* __restrict__ u,
    const float* __restrict__ v,
    const float* __restrict__ wgt,
    float* __restrict__ out,
    int N)
{
    constexpr float INV_SQRT3 = 0.57735026918962576451f; // 1/sqrt(3)
    constexpr float PW0 = 0.17677669529663688110f;       // sqrt(1/32)
    constexpr float PW1 = 0.30618621784789726f;          // sqrt(3/32)

    const int lane = threadIdx.x & 63;
    const int wv   = threadIdx.x >> 6;      // wave within block (0..3)
    int n = blockIdx.x * 4 + wv;
    if (n >= N) n = N - 1;                  // benign, deterministic

    // per-wave LDS: [0..63] = u row, [64..79] = d4[u], [80..83] = v row
    __shared__ float sh[4][84];
    float* s = sh[wv];

    // ---- stage u and v (coalesced) ----
    s[lane] = u[(size_t)n * 64 + lane];
    if (lane < 4) s[80 + lane] = v[(size_t)n * 4 + lane];
    __syncthreads();

    // ---- d4[u] = dot(u1[u,:], v1) computed by lanes 0..15 ----
    if (lane < 16) {
        const int b = 16 + 3 * lane;
        s[64 + lane] = s[b] * s[81] + s[b + 1] * s[82] + s[b + 2] * s[83];
    }
    __syncthreads();

    // ---- per-lane constants ----
    const bool is0 = (lane < 16);
    const int  o    = lane - 16;            // 0..47 for the l=1 outputs
    const int  wcol = is0 ? lane : (o / 3); // weight column this lane consumes
    const int  k    = is0 ? 0    : (o - 3 * wcol);
    const float v0  = s[80];
    const float p   = is0 ? v0        : s[81 + k] * INV_SQRT3;
    const float q   = is0 ? INV_SQRT3 : v0 * INV_SQRT3;
    // weight element offsets within this edge's 1024-float block:
    //   w1 @ 0, w2 @ 256, w3 @ 512, w4 @ 768 ; element [u][col] at u*16+col
    const int offA = is0 ? wcol         : (256 + wcol); // w1 : w2
    const int offB = is0 ? (768 + wcol) : (512 + wcol); // w4 : w3
    const int offY  = is0 ? 64 : (16 + k);              // d4[u] vs u1[u][k]
    const int ystep = is0 ? 1 : 3;

    const float* wp = wgt + (size_t)n * 1024;

    float acc = 0.0f;
#pragma unroll
    for (int uu = 0; uu < 16; ++uu) {
        const float X  = s[uu];                 // u0[u]  (LDS broadcast)
        const float Y  = s[offY + uu * ystep];  // d4[u] or u1[u][k]
        const float wa = wp[offA + uu * 16];    // column read, coalesced across wave
        const float wb = wp[offB + uu * 16];
        acc = fmaf(wa, X * p, acc);
        acc = fmaf(wb, Y * q, acc);
    }

    out[(size_t)n * 64 + lane] = (is0 ? PW0 : PW1) * acc;
}

extern "C" void kernel_launch(void* const* d_in, const int* in_sizes, int n_in,
                              void* d_out, int out_size, void* d_ws, size_t ws_size,
                              hipStream_t stream)
{
    const float* u   = (const float*)d_in[0];
    const float* v   = (const float*)d_in[1];
    const float* wgt = (const float*)d_in[2];
    float* out = (float*)d_out;

    const int N = in_sizes[1] / 4;      // v is (N,4)
    const int blocks = (N + 3) / 4;     // 4 edges (waves) per 256-thread block
    fctp_kernel<<<blocks, 256, 0, stream>>>(u, v, wgt, out, N);
}